// Round 6
// baseline (262.482 us; speedup 1.0000x reference)
//
#include <hip/hip_runtime.h>
#include <hip/hip_bf16.h>
#include <cstddef>

typedef __attribute__((ext_vector_type(8))) short short8;
typedef __attribute__((ext_vector_type(4))) float f32x4;

__device__ inline unsigned short f2bf(float f) {
  unsigned int u = __float_as_uint(f);
  u += 0x7fffu + ((u >> 16) & 1u);
  return (unsigned short)(u >> 16);
}
__device__ inline unsigned int pkbf(float a, float b) {
  __hip_bfloat162 h = __float22bfloat162_rn(make_float2(a, b));
  union { __hip_bfloat162 h2; unsigned int u; } cv;
  cv.h2 = h;
  return cv.u;
}

// transpose + cast: src [R,C] f32 -> dst [C,R] bf16
__global__ __launch_bounds__(256) void tcast_kernel(const float* __restrict__ src,
                                                    unsigned short* __restrict__ dst,
                                                    int R, int C) {
  __shared__ float tile[64][65];
  int c0 = blockIdx.x * 64, r0 = blockIdx.y * 64;
  int tx = threadIdx.x & 63, ty = threadIdx.x >> 6;
  for (int i = ty; i < 64; i += 4)
    tile[i][tx] = src[(size_t)(r0 + i) * C + c0 + tx];
  __syncthreads();
  for (int i = ty; i < 64; i += 4)
    dst[(size_t)(c0 + i) * R + r0 + tx] = f2bf(tile[tx][i]);
}

// pack key mask into 64-bit words: mpk[g] bit i = (mask[g*64+i] != 0)
__global__ __launch_bounds__(64) void maskpack_kernel(const int* __restrict__ mask,
                                                      unsigned long long* __restrict__ mpk) {
  int gid = blockIdx.x * 64 + threadIdx.x;
  unsigned long long bal = __ballot(mask[gid] != 0);
  if (threadIdx.x == 0) mpk[blockIdx.x] = bal;
}

// C = A[M,K] * Bt[N,K]^T. Block tile (MT*32) x 128, 4 waves 2x2, T14 prefetch.
// MODE 0: C0 bf16 [M,N] scaled by oscale
// MODE 1: split kv: col<512 -> C0 bf16 [M,512]; col>=512 -> C1 vt[b,h,d,m]
// MODE 2: C0 f32 [M,N] + bias
template <int MT, int MODE, bool AF32>
__global__ __launch_bounds__(256) void gemm_kernel(
    const void* __restrict__ Ap, const unsigned short* __restrict__ Bt,
    void* __restrict__ C0, unsigned short* __restrict__ C1,
    const float* __restrict__ bias, int M, int N, int K, float oscale) {
  __shared__ unsigned short As[MT * 32][72];
  __shared__ unsigned short Bs[128][72];
  const int bm = blockIdx.y * (MT * 32), bn = blockIdx.x * 128;
  const int tid = threadIdx.x;
  const int wave = tid >> 6, lane = tid & 63;
  const int wr = (wave >> 1) * (MT * 16), wc = (wave & 1) * 64;
  const int l15 = lane & 15, lq = lane >> 4;
  const int sr = tid >> 3, sc = (tid & 7) * 8;
  f32x4 acc[MT][4] = {};

  const float* Af = (const float*)Ap;
  const unsigned short* Ab = (const unsigned short*)Ap;

  float4 fa[MT][2];
  uint4 ua[MT];
  uint4 ub[4];

  auto load_chunk = [&](int k0) {
#pragma unroll
    for (int p = 0; p < MT; ++p) {
      if constexpr (AF32) {
        fa[p][0] = *(const float4*)(Af + (size_t)(bm + sr + p * 32) * K + k0 + sc);
        fa[p][1] = *(const float4*)(Af + (size_t)(bm + sr + p * 32) * K + k0 + sc + 4);
      } else {
        ua[p] = *(const uint4*)(Ab + (size_t)(bm + sr + p * 32) * K + k0 + sc);
      }
    }
#pragma unroll
    for (int p = 0; p < 4; ++p)
      ub[p] = *(const uint4*)(Bt + (size_t)(bn + sr + p * 32) * K + k0 + sc);
  };

  load_chunk(0);

  for (int k0 = 0; k0 < K; k0 += 64) {
    __syncthreads();  // BAR-A: prev-tile LDS reads done; vmcnt drain = our staged data
#pragma unroll
    for (int p = 0; p < MT; ++p) {
      if constexpr (AF32) {
        uint4 u;
        u.x = pkbf(fa[p][0].x, fa[p][0].y);
        u.y = pkbf(fa[p][0].z, fa[p][0].w);
        u.z = pkbf(fa[p][1].x, fa[p][1].y);
        u.w = pkbf(fa[p][1].z, fa[p][1].w);
        *(uint4*)(&As[sr + p * 32][sc]) = u;
      } else {
        *(uint4*)(&As[sr + p * 32][sc]) = ua[p];
      }
    }
#pragma unroll
    for (int p = 0; p < 4; ++p)
      *(uint4*)(&Bs[sr + p * 32][sc]) = ub[p];
    if (k0 + 64 < K) load_chunk(k0 + 64);  // prefetch: lands during compute
    asm volatile("s_waitcnt lgkmcnt(0)" ::: "memory");
    __builtin_amdgcn_s_barrier();  // BAR-B (no vmcnt drain -> prefetch stays in flight)
#pragma unroll
    for (int kk = 0; kk < 2; ++kk) {
      short8 af[MT], bfr[4];
#pragma unroll
      for (int mt = 0; mt < MT; ++mt)
        af[mt] = *(const short8*)(&As[wr + mt * 16 + l15][kk * 32 + lq * 8]);
#pragma unroll
      for (int nt = 0; nt < 4; ++nt)
        bfr[nt] = *(const short8*)(&Bs[wc + nt * 16 + l15][kk * 32 + lq * 8]);
#pragma unroll
      for (int mt = 0; mt < MT; ++mt)
#pragma unroll
        for (int nt = 0; nt < 4; ++nt)
          acc[mt][nt] = __builtin_amdgcn_mfma_f32_16x16x32_bf16(af[mt], bfr[nt], acc[mt][nt], 0, 0, 0);
    }
  }

#pragma unroll
  for (int mt = 0; mt < MT; ++mt)
#pragma unroll
    for (int nt = 0; nt < 4; ++nt)
#pragma unroll
      for (int j = 0; j < 4; ++j) {
        int row = bm + wr + mt * 16 + lq * 4 + j;
        int col = bn + wc + nt * 16 + l15;
        float v = acc[mt][nt][j];
        if constexpr (MODE == 0) {
          ((unsigned short*)C0)[(size_t)row * N + col] = f2bf(v * oscale);
        } else if constexpr (MODE == 1) {
          if (col < 512) {
            ((unsigned short*)C0)[(size_t)row * 512 + col] = f2bf(v);
          } else {
            int bb = row >> 11, m = row & 2047;
            int hd = col - 512;  // h*64+d
            C1[((size_t)bb * 512 + hd) * 2048 + m] = f2bf(v);
          }
        } else {
          ((float*)C0)[(size_t)row * N + col] = v + bias[col];
        }
      }
}

// Flash attention, swapped-MFMA in-register softmax, T14 async staging.
// Q (pre-scaled by scale*log2e) / K: [B*2048, 512] bf16. Vt: [b,h,d,m] bf16.
// Mask as packed 64-bit words (one per 64-key tile).
// 4 waves x 16 q-rows = 64 q-rows/block, KV tile 64; 256 threads.
// launch_bounds(256,3): budget ~170 VGPR >= demand (~140) -> NO SPILL.
// (256,4) forced a 128-VGPR budget < demand -> 160-200MB scratch traffic (r4/r5).
__global__ __launch_bounds__(256, 3) void attn_kernel(
    const unsigned short* __restrict__ Q, const unsigned short* __restrict__ Kb,
    const unsigned short* __restrict__ Vt, const unsigned long long* __restrict__ Mpk,
    unsigned short* __restrict__ O) {
  __shared__ unsigned short Ks[64][72];
  __shared__ unsigned short Vs[64][72];
  const int b = blockIdx.x >> 3, h = blockIdx.x & 7;
  const int tid = threadIdx.x, wave = tid >> 6, lane = tid & 63;
  const int l15 = lane & 15, lq = lane >> 4;
  const int wrow = blockIdx.y * 64 + wave * 16;

  // Q fragments: lane holds q-col = l15, d-elems lq*8..+7
  short8 qf[2];
#pragma unroll
  for (int kk = 0; kk < 2; ++kk)
    qf[kk] = *(const short8*)(Q + (size_t)(b * 2048 + wrow + l15) * 512
                                + h * 64 + kk * 32 + lq * 8);

  f32x4 o[4] = {};  // O^T[d = dt*16+lq*4+j][q = l15]
  float mrun = -1e30f, lrun = 0.f;

  const unsigned short* Kg = Kb + (size_t)b * 2048 * 512 + h * 64;
  const unsigned short* Vg = Vt + (size_t)(b * 8 + h) * 64 * 2048;
  const unsigned long long* mp = Mpk + b * 32;

  const int str = tid >> 3;        // 0..31
  const int stc = (tid & 7) * 8;   // elem col within 64

  uint4 kreg[2], vreg[2];
  unsigned long long mreg;

  auto stage_load = [&](int mb) {
#pragma unroll
    for (int i = 0; i < 2; ++i)
      kreg[i] = *(const uint4*)(Kg + (size_t)(mb + str + i * 32) * 512 + stc);
#pragma unroll
    for (int i = 0; i < 2; ++i)
      vreg[i] = *(const uint4*)(Vg + (size_t)(str + i * 32) * 2048 + mb + stc);
    mreg = mp[mb >> 6];
  };

  stage_load(0);

  for (int mb = 0; mb < 2048; mb += 64) {
    __syncthreads();  // BAR-A: prev compute's LDS reads done; drains our staged loads
#pragma unroll
    for (int i = 0; i < 2; ++i)
      *(uint4*)(&Ks[str + i * 32][stc]) = kreg[i];
#pragma unroll
    for (int i = 0; i < 2; ++i)
      *(uint4*)(&Vs[str + i * 32][stc]) = vreg[i];
    unsigned long long mcur = mreg;  // snapshot before prefetch overwrites
    if (mb + 64 < 2048) stage_load(mb + 64);  // prefetch, lands during compute
    asm volatile("s_waitcnt lgkmcnt(0)" ::: "memory");
    __builtin_amdgcn_s_barrier();  // BAR-B: tile visible; prefetch stays in flight

    // swapped QK^T: s[ct] = S^T[key = ct*16+lq*4+j][q = l15]
    f32x4 s[4] = {};
#pragma unroll
    for (int kk = 0; kk < 2; ++kk) {
      short8 kf[4];
#pragma unroll
      for (int ct = 0; ct < 4; ++ct)
        kf[ct] = *(const short8*)(&Ks[ct * 16 + l15][kk * 32 + lq * 8]);
#pragma unroll
      for (int ct = 0; ct < 4; ++ct)
        s[ct] = __builtin_amdgcn_mfma_f32_16x16x32_bf16(kf[ct], qf[kk], s[ct], 0, 0, 0);
    }

    // apply mask from scalar-ized bitmask: key = ct*16 + lq*4 + j
    unsigned int mlo = __builtin_amdgcn_readfirstlane((unsigned int)mcur);
    unsigned int mhi = __builtin_amdgcn_readfirstlane((unsigned int)(mcur >> 32));
#pragma unroll
    for (int ct = 0; ct < 4; ++ct) {
      unsigned int ch = ((ct < 2) ? mlo : mhi) >> ((ct & 1) * 16);  // scalar
      unsigned int nib = (ch >> (lq * 4)) & 0xFu;
#pragma unroll
      for (int j = 0; j < 4; ++j)
        s[ct][j] = (nib & (1u << j)) ? s[ct][j] : -1e30f;
    }

    float t = -1e30f;
#pragma unroll
    for (int ct = 0; ct < 4; ++ct)
#pragma unroll
      for (int j = 0; j < 4; ++j)
        t = fmaxf(t, s[ct][j]);
    t = fmaxf(t, __shfl_xor(t, 16));
    t = fmaxf(t, __shfl_xor(t, 32));
    float mn = fmaxf(mrun, t);
    float fac = __builtin_amdgcn_exp2f(mrun - mn);
    mrun = mn;
    float rs = 0.f;
    unsigned int xp[4][2];  // bf16 pairs: keys ct*16+lq*4+{2p,2p+1}
#pragma unroll
    for (int ct = 0; ct < 4; ++ct) {
      float p0 = __builtin_amdgcn_exp2f(s[ct][0] - mn);
      float p1 = __builtin_amdgcn_exp2f(s[ct][1] - mn);
      float p2 = __builtin_amdgcn_exp2f(s[ct][2] - mn);
      float p3 = __builtin_amdgcn_exp2f(s[ct][3] - mn);
      rs += (p0 + p1) + (p2 + p3);
      xp[ct][0] = pkbf(p0, p1);
      xp[ct][1] = pkbf(p2, p3);
    }
    rs += __shfl_xor(rs, 16);
    rs += __shfl_xor(rs, 32);
    lrun = lrun * fac + rs;
#pragma unroll
    for (int dt = 0; dt < 4; ++dt)
#pragma unroll
      for (int j = 0; j < 4; ++j)
        o[dt][j] *= fac;

    // redistribute P^T into PV B-fragments:
    // dest reg r needs xp[kk*2 + (lq>>1)][r&1] from lane ((lq&1)*2 + (r>>1))*16 + l15
    unsigned int pf[2][4];
    const int slbase = ((lq & 1) * 2) * 16 + l15;
#pragma unroll
    for (int kk = 0; kk < 2; ++kk)
#pragma unroll
      for (int r = 0; r < 4; ++r) {
        int sl = (slbase + (r >> 1) * 16) << 2;
        unsigned a0 = (unsigned)__builtin_amdgcn_ds_bpermute(sl, (int)xp[kk * 2 + 0][r & 1]);
        unsigned a1 = (unsigned)__builtin_amdgcn_ds_bpermute(sl, (int)xp[kk * 2 + 1][r & 1]);
        pf[kk][r] = (lq >> 1) ? a1 : a0;
      }

    // PV swapped: O^T += V^T · P^T
#pragma unroll
    for (int kk = 0; kk < 2; ++kk) {
      union { unsigned int u[4]; short8 s8; } pc;
      pc.u[0] = pf[kk][0];
      pc.u[1] = pf[kk][1];
      pc.u[2] = pf[kk][2];
      pc.u[3] = pf[kk][3];
#pragma unroll
      for (int dt = 0; dt < 4; ++dt) {
        short8 vf = *(const short8*)(&Vs[dt * 16 + l15][kk * 32 + lq * 8]);
        o[dt] = __builtin_amdgcn_mfma_f32_16x16x32_bf16(vf, pc.s8, o[dt], 0, 0, 0);
      }
    }
  }

  float rl = 1.0f / lrun;
  unsigned short* Orow = O + (size_t)(b * 2048 + wrow + l15) * 512 + h * 64;
#pragma unroll
  for (int dt = 0; dt < 4; ++dt) {
    *(unsigned int*)(Orow + dt * 16 + lq * 4)     = pkbf(o[dt][0] * rl, o[dt][1] * rl);
    *(unsigned int*)(Orow + dt * 16 + lq * 4 + 2) = pkbf(o[dt][2] * rl, o[dt][3] * rl);
  }
}

extern "C" void kernel_launch(void* const* d_in, const int* in_sizes, int n_in,
                              void* d_out, int out_size, void* d_ws, size_t ws_size,
                              hipStream_t stream) {
  const float* x       = (const float*)d_in[0];
  const float* context = (const float*)d_in[1];
  const int*   mask    = (const int*)d_in[2];
  const float* Wq      = (const float*)d_in[3];
  const float* Wkv     = (const float*)d_in[4];
  const float* Wo      = (const float*)d_in[5];
  const float* bo      = (const float*)d_in[6];
  float* out = (float*)d_out;

  char* ws = (char*)d_ws;
  unsigned short* Wq_t  = (unsigned short*)(ws + 0);         //  512x512  bf16
  unsigned short* Wkv_t = (unsigned short*)(ws + 524288);    // 1024x512  bf16
  unsigned short* Wo_t  = (unsigned short*)(ws + 1572864);   //  512x512  bf16
  unsigned short* qb    = (unsigned short*)(ws + 2097152);   // 8192x512  bf16
  unsigned short* kb    = (unsigned short*)(ws + 10485760);  // 8192x512  bf16
  unsigned short* vtb   = (unsigned short*)(ws + 18874368);  // (b,h,d)x2048 bf16
  unsigned short* ab    = (unsigned short*)(ws + 27262976);  // 8192x512  bf16
  unsigned long long* mpk = (unsigned long long*)(ws + 35651584);  // 128 x u64

  const float QSCALE = 0.125f * 1.44269504088896f;  // head_dim^-0.5 * log2(e)

  tcast_kernel<<<dim3(8, 8), 256, 0, stream>>>(Wq, Wq_t, 512, 512);
  tcast_kernel<<<dim3(16, 8), 256, 0, stream>>>(Wkv, Wkv_t, 512, 1024);
  tcast_kernel<<<dim3(8, 8), 256, 0, stream>>>(Wo, Wo_t, 512, 512);
  maskpack_kernel<<<dim3(128), 64, 0, stream>>>(mask, mpk);
  gemm_kernel<4, 0, true><<<dim3(4, 64), 256, 0, stream>>>(x, Wq_t, qb, nullptr, nullptr, 8192, 512, 512, QSCALE);
  gemm_kernel<4, 1, true><<<dim3(8, 64), 256, 0, stream>>>(context, Wkv_t, kb, vtb, nullptr, 8192, 1024, 512, 1.0f);
  attn_kernel<<<dim3(32, 32), 256, 0, stream>>>(qb, kb, vtb, mpk, ab);
  gemm_kernel<4, 2, false><<<dim3(4, 64), 256, 0, stream>>>(ab, Wo_t, out, nullptr, bo, 8192, 512, 512, 1.0f);
}

// Round 7
// 178.267 us; speedup vs baseline: 1.4724x; 1.4724x over previous
//
#include <hip/hip_runtime.h>
#include <hip/hip_bf16.h>
#include <cstddef>

typedef __attribute__((ext_vector_type(8))) short short8;
typedef __attribute__((ext_vector_type(4))) float f32x4;

__device__ inline unsigned short f2bf(float f) {
  unsigned int u = __float_as_uint(f);
  u += 0x7fffu + ((u >> 16) & 1u);
  return (unsigned short)(u >> 16);
}
__device__ inline unsigned int pkbf(float a, float b) {
  __hip_bfloat162 h = __float22bfloat162_rn(make_float2(a, b));
  union { __hip_bfloat162 h2; unsigned int u; } cv;
  cv.h2 = h;
  return cv.u;
}

// transpose + cast: src [R,C] f32 -> dst [C,R] bf16
__global__ __launch_bounds__(256) void tcast_kernel(const float* __restrict__ src,
                                                    unsigned short* __restrict__ dst,
                                                    int R, int C) {
  __shared__ float tile[64][65];
  int c0 = blockIdx.x * 64, r0 = blockIdx.y * 64;
  int tx = threadIdx.x & 63, ty = threadIdx.x >> 6;
  for (int i = ty; i < 64; i += 4)
    tile[i][tx] = src[(size_t)(r0 + i) * C + c0 + tx];
  __syncthreads();
  for (int i = ty; i < 64; i += 4)
    dst[(size_t)(c0 + i) * R + r0 + tx] = f2bf(tile[tx][i]);
}

// pack key mask into 64-bit words: mpk[g] bit i = (mask[g*64+i] != 0)
__global__ __launch_bounds__(64) void maskpack_kernel(const int* __restrict__ mask,
                                                      unsigned long long* __restrict__ mpk) {
  int gid = blockIdx.x * 64 + threadIdx.x;
  unsigned long long bal = __ballot(mask[gid] != 0);
  if (threadIdx.x == 0) mpk[blockIdx.x] = bal;
}

// C = A[M,K] * Bt[N,K]^T. Round-2 structure: direct global->LDS staging,
// two __syncthreads per K-step, NO lambdas, NO inline asm (scratch-safe).
// MODE 0: C0 bf16 [M,N] scaled by oscale
// MODE 1: split kv: col<512 -> C0 bf16 [M,512]; col>=512 -> C1 vt[b,h,d,m]
// MODE 2: C0 f32 [M,N] + bias
template <int MT, int MODE, bool AF32>
__global__ __launch_bounds__(256) void gemm_kernel(
    const void* __restrict__ Ap, const unsigned short* __restrict__ Bt,
    void* __restrict__ C0, unsigned short* __restrict__ C1,
    const float* __restrict__ bias, int M, int N, int K, float oscale) {
  __shared__ unsigned short As[MT * 32][72];
  __shared__ unsigned short Bs[128][72];
  const int bm = blockIdx.y * (MT * 32), bn = blockIdx.x * 128;
  const int tid = threadIdx.x;
  const int wave = tid >> 6, lane = tid & 63;
  const int wr = (wave >> 1) * (MT * 16), wc = (wave & 1) * 64;
  const int l15 = lane & 15, lq = lane >> 4;
  const int sr = tid >> 3, sc = (tid & 7) * 8;
  f32x4 acc[MT][4] = {};

  const float* Af = (const float*)Ap;
  const unsigned short* Ab = (const unsigned short*)Ap;

  for (int k0 = 0; k0 < K; k0 += 64) {
    __syncthreads();
#pragma unroll
    for (int p = 0; p < MT; ++p) {
      int r = sr + p * 32;
      if constexpr (AF32) {
        const float4 f0 = *(const float4*)(Af + (size_t)(bm + r) * K + k0 + sc);
        const float4 f1 = *(const float4*)(Af + (size_t)(bm + r) * K + k0 + sc + 4);
        uint4 u;
        u.x = pkbf(f0.x, f0.y);
        u.y = pkbf(f0.z, f0.w);
        u.z = pkbf(f1.x, f1.y);
        u.w = pkbf(f1.z, f1.w);
        *(uint4*)(&As[r][sc]) = u;
      } else {
        *(uint4*)(&As[r][sc]) = *(const uint4*)(Ab + (size_t)(bm + r) * K + k0 + sc);
      }
    }
#pragma unroll
    for (int p = 0; p < 4; ++p)
      *(uint4*)(&Bs[sr + p * 32][sc]) = *(const uint4*)(Bt + (size_t)(bn + sr + p * 32) * K + k0 + sc);
    __syncthreads();
#pragma unroll
    for (int kk = 0; kk < 2; ++kk) {
      short8 af[MT], bfr[4];
#pragma unroll
      for (int mt = 0; mt < MT; ++mt)
        af[mt] = *(const short8*)(&As[wr + mt * 16 + l15][kk * 32 + lq * 8]);
#pragma unroll
      for (int nt = 0; nt < 4; ++nt)
        bfr[nt] = *(const short8*)(&Bs[wc + nt * 16 + l15][kk * 32 + lq * 8]);
#pragma unroll
      for (int mt = 0; mt < MT; ++mt)
#pragma unroll
        for (int nt = 0; nt < 4; ++nt)
          acc[mt][nt] = __builtin_amdgcn_mfma_f32_16x16x32_bf16(af[mt], bfr[nt], acc[mt][nt], 0, 0, 0);
    }
  }

#pragma unroll
  for (int mt = 0; mt < MT; ++mt)
#pragma unroll
    for (int nt = 0; nt < 4; ++nt)
#pragma unroll
      for (int j = 0; j < 4; ++j) {
        int row = bm + wr + mt * 16 + lq * 4 + j;
        int col = bn + wc + nt * 16 + l15;
        float v = acc[mt][nt][j];
        if constexpr (MODE == 0) {
          ((unsigned short*)C0)[(size_t)row * N + col] = f2bf(v * oscale);
        } else if constexpr (MODE == 1) {
          if (col < 512) {
            ((unsigned short*)C0)[(size_t)row * 512 + col] = f2bf(v);
          } else {
            int bb = row >> 11, m = row & 2047;
            int hd = col - 512;  // h*64+d
            C1[((size_t)bb * 512 + hd) * 2048 + m] = f2bf(v);
          }
        } else {
          ((float*)C0)[(size_t)row * N + col] = v + bias[col];
        }
      }
}

// Flash attention, swapped-MFMA in-register softmax.
// Double-buffered LDS, ONE __syncthreads per KV-tile, no inline asm, no
// lambdas, no launch_bounds minimum (scratch-safe: all locals are named
// scalars, nothing address-taken).
// Pipeline per tile t: [use prefetch regs] ds_write buf[t&1] -> barrier ->
// issue prefetch t+1 -> compute from buf[t&1]. Prefetch loads never cross a
// draining barrier; WAR on buf separated by previous iteration's barrier.
// Q (pre-scaled by scale*log2e) / K: [B*2048, 512] bf16. Vt: [b,h,d,m] bf16.
// 4 waves x 16 q-rows = 64 q-rows/block; 256 threads.
// blockIdx.x = bh (fast-varying -> per-XCD K/V L2 residency), blockIdx.y = q-chunk.
__global__ __launch_bounds__(256) void attn_kernel(
    const unsigned short* __restrict__ Q, const unsigned short* __restrict__ Kb,
    const unsigned short* __restrict__ Vt, const unsigned long long* __restrict__ Mpk,
    unsigned short* __restrict__ O) {
  __shared__ unsigned short Ks[2][64][72];
  __shared__ unsigned short Vs[2][64][72];
  const int b = blockIdx.x >> 3, h = blockIdx.x & 7;
  const int tid = threadIdx.x, lane = tid & 63;
  const int wave = tid >> 6;
  const int l15 = lane & 15, lq = lane >> 4;
  const int wrow = blockIdx.y * 64 + wave * 16;

  // Q fragments: lane holds q-col = l15, d-elems lq*8..+7
  short8 qf0 = *(const short8*)(Q + (size_t)(b * 2048 + wrow + l15) * 512 + h * 64 + lq * 8);
  short8 qf1 = *(const short8*)(Q + (size_t)(b * 2048 + wrow + l15) * 512 + h * 64 + 32 + lq * 8);

  f32x4 o[4] = {};  // O^T[d = dt*16+lq*4+j][q = l15]
  float mrun = -1e30f, lrun = 0.f;

  const unsigned short* Kg = Kb + (size_t)b * 2048 * 512 + h * 64;
  const unsigned short* Vg = Vt + (size_t)(b * 8 + h) * 64 * 2048;
  const unsigned long long* mp = Mpk + b * 32;

  const int str = tid >> 3;        // 0..31
  const int stc = (tid & 7) * 8;   // elem col within 64

  // prefetch tile 0 (named scalars only)
  uint4 kr0 = *(const uint4*)(Kg + (size_t)str * 512 + stc);
  uint4 kr1 = *(const uint4*)(Kg + (size_t)(str + 32) * 512 + stc);
  uint4 vr0 = *(const uint4*)(Vg + (size_t)str * 2048 + stc);
  uint4 vr1 = *(const uint4*)(Vg + (size_t)(str + 32) * 2048 + stc);
  unsigned long long mreg = mp[0];

  for (int mb = 0; mb < 2048; mb += 64) {
    const int buf = (mb >> 6) & 1;
    // implicit vmcnt wait on kr*/vr* here (thread-local)
    *(uint4*)(&Ks[buf][str][stc]) = kr0;
    *(uint4*)(&Ks[buf][str + 32][stc]) = kr1;
    *(uint4*)(&Vs[buf][str][stc]) = vr0;
    *(uint4*)(&Vs[buf][str + 32][stc]) = vr1;
    unsigned long long mcur = mreg;
    __syncthreads();  // write->read sync for buf; prefetch below never crosses a barrier
    if (mb + 64 < 2048) {
      kr0 = *(const uint4*)(Kg + (size_t)(mb + 64 + str) * 512 + stc);
      kr1 = *(const uint4*)(Kg + (size_t)(mb + 64 + str + 32) * 512 + stc);
      vr0 = *(const uint4*)(Vg + (size_t)str * 2048 + mb + 64 + stc);
      vr1 = *(const uint4*)(Vg + (size_t)(str + 32) * 2048 + mb + 64 + stc);
      mreg = mp[(mb >> 6) + 1];
    }

    // swapped QK^T: s[ct] = S^T[key = ct*16+lq*4+j][q = l15]
    f32x4 s[4] = {};
#pragma unroll
    for (int ct = 0; ct < 4; ++ct) {
      short8 kf = *(const short8*)(&Ks[buf][ct * 16 + l15][lq * 8]);
      s[ct] = __builtin_amdgcn_mfma_f32_16x16x32_bf16(kf, qf0, s[ct], 0, 0, 0);
    }
#pragma unroll
    for (int ct = 0; ct < 4; ++ct) {
      short8 kf = *(const short8*)(&Ks[buf][ct * 16 + l15][32 + lq * 8]);
      s[ct] = __builtin_amdgcn_mfma_f32_16x16x32_bf16(kf, qf1, s[ct], 0, 0, 0);
    }

    // apply mask from scalar-ized bitmask: key = ct*16 + lq*4 + j
    unsigned int mlo = __builtin_amdgcn_readfirstlane((unsigned int)mcur);
    unsigned int mhi = __builtin_amdgcn_readfirstlane((unsigned int)(mcur >> 32));
#pragma unroll
    for (int ct = 0; ct < 4; ++ct) {
      unsigned int ch = ((ct < 2) ? mlo : mhi) >> ((ct & 1) * 16);  // scalar
      unsigned int nib = (ch >> (lq * 4)) & 0xFu;
#pragma unroll
      for (int j = 0; j < 4; ++j)
        s[ct][j] = (nib & (1u << j)) ? s[ct][j] : -1e30f;
    }

    float t = -1e30f;
#pragma unroll
    for (int ct = 0; ct < 4; ++ct)
#pragma unroll
      for (int j = 0; j < 4; ++j)
        t = fmaxf(t, s[ct][j]);
    t = fmaxf(t, __shfl_xor(t, 16));
    t = fmaxf(t, __shfl_xor(t, 32));
    float mn = fmaxf(mrun, t);
    float fac = __builtin_amdgcn_exp2f(mrun - mn);
    mrun = mn;
    float rs = 0.f;
    unsigned int xp[4][2];  // bf16 pairs: keys ct*16+lq*4+{2p,2p+1}
#pragma unroll
    for (int ct = 0; ct < 4; ++ct) {
      float p0 = __builtin_amdgcn_exp2f(s[ct][0] - mn);
      float p1 = __builtin_amdgcn_exp2f(s[ct][1] - mn);
      float p2 = __builtin_amdgcn_exp2f(s[ct][2] - mn);
      float p3 = __builtin_amdgcn_exp2f(s[ct][3] - mn);
      rs += (p0 + p1) + (p2 + p3);
      xp[ct][0] = pkbf(p0, p1);
      xp[ct][1] = pkbf(p2, p3);
    }
    rs += __shfl_xor(rs, 16);
    rs += __shfl_xor(rs, 32);
    lrun = lrun * fac + rs;
#pragma unroll
    for (int dt = 0; dt < 4; ++dt)
#pragma unroll
      for (int j = 0; j < 4; ++j)
        o[dt][j] *= fac;

    // redistribute P^T into PV B-fragments:
    // dest reg r needs xp[kk*2 + (lq>>1)][r&1] from lane ((lq&1)*2 + (r>>1))*16 + l15
    unsigned int pf[2][4];
    const int slbase = ((lq & 1) * 2) * 16 + l15;
#pragma unroll
    for (int kk = 0; kk < 2; ++kk)
#pragma unroll
      for (int r = 0; r < 4; ++r) {
        int sl = (slbase + (r >> 1) * 16) << 2;
        unsigned a0 = (unsigned)__builtin_amdgcn_ds_bpermute(sl, (int)xp[kk * 2 + 0][r & 1]);
        unsigned a1 = (unsigned)__builtin_amdgcn_ds_bpermute(sl, (int)xp[kk * 2 + 1][r & 1]);
        pf[kk][r] = (lq >> 1) ? a1 : a0;
      }

    // PV swapped: O^T += V^T · P^T
#pragma unroll
    for (int kk = 0; kk < 2; ++kk) {
      union { unsigned int u[4]; short8 s8; } pc;
      pc.u[0] = pf[kk][0];
      pc.u[1] = pf[kk][1];
      pc.u[2] = pf[kk][2];
      pc.u[3] = pf[kk][3];
#pragma unroll
      for (int dt = 0; dt < 4; ++dt) {
        short8 vf = *(const short8*)(&Vs[buf][dt * 16 + l15][kk * 32 + lq * 8]);
        o[dt] = __builtin_amdgcn_mfma_f32_16x16x32_bf16(vf, pc.s8, o[dt], 0, 0, 0);
      }
    }
  }

  float rl = 1.0f / lrun;
  unsigned short* Orow = O + (size_t)(b * 2048 + wrow + l15) * 512 + h * 64;
#pragma unroll
  for (int dt = 0; dt < 4; ++dt) {
    *(unsigned int*)(Orow + dt * 16 + lq * 4)     = pkbf(o[dt][0] * rl, o[dt][1] * rl);
    *(unsigned int*)(Orow + dt * 16 + lq * 4 + 2) = pkbf(o[dt][2] * rl, o[dt][3] * rl);
  }
}

extern "C" void kernel_launch(void* const* d_in, const int* in_sizes, int n_in,
                              void* d_out, int out_size, void* d_ws, size_t ws_size,
                              hipStream_t stream) {
  const float* x       = (const float*)d_in[0];
  const float* context = (const float*)d_in[1];
  const int*   mask    = (const int*)d_in[2];
  const float* Wq      = (const float*)d_in[3];
  const float* Wkv     = (const float*)d_in[4];
  const float* Wo      = (const float*)d_in[5];
  const float* bo      = (const float*)d_in[6];
  float* out = (float*)d_out;

  char* ws = (char*)d_ws;
  unsigned short* Wq_t  = (unsigned short*)(ws + 0);         //  512x512  bf16
  unsigned short* Wkv_t = (unsigned short*)(ws + 524288);    // 1024x512  bf16
  unsigned short* Wo_t  = (unsigned short*)(ws + 1572864);   //  512x512  bf16
  unsigned short* qb    = (unsigned short*)(ws + 2097152);   // 8192x512  bf16
  unsigned short* kb    = (unsigned short*)(ws + 10485760);  // 8192x512  bf16
  unsigned short* vtb   = (unsigned short*)(ws + 18874368);  // (b,h,d)x2048 bf16
  unsigned short* ab    = (unsigned short*)(ws + 27262976);  // 8192x512  bf16
  unsigned long long* mpk = (unsigned long long*)(ws + 35651584);  // 128 x u64

  const float QSCALE = 0.125f * 1.44269504088896f;  // head_dim^-0.5 * log2(e)

  tcast_kernel<<<dim3(8, 8), 256, 0, stream>>>(Wq, Wq_t, 512, 512);
  tcast_kernel<<<dim3(16, 8), 256, 0, stream>>>(Wkv, Wkv_t, 512, 1024);
  tcast_kernel<<<dim3(8, 8), 256, 0, stream>>>(Wo, Wo_t, 512, 512);
  maskpack_kernel<<<dim3(128), 64, 0, stream>>>(mask, mpk);
  gemm_kernel<4, 0, true><<<dim3(4, 64), 256, 0, stream>>>(x, Wq_t, qb, nullptr, nullptr, 8192, 512, 512, QSCALE);
  gemm_kernel<4, 1, true><<<dim3(8, 64), 256, 0, stream>>>(context, Wkv_t, kb, vtb, nullptr, 8192, 1024, 512, 1.0f);
  attn_kernel<<<dim3(32, 32), 256, 0, stream>>>(qb, kb, vtb, mpk, ab);
  gemm_kernel<4, 2, false><<<dim3(4, 64), 256, 0, stream>>>(ab, Wo_t, out, nullptr, bo, 8192, 512, 512, 1.0f);
}

// Round 8
// 177.674 us; speedup vs baseline: 1.4773x; 1.0033x over previous
//
#include <hip/hip_runtime.h>
#include <hip/hip_bf16.h>
#include <cstddef>

typedef __attribute__((ext_vector_type(8))) short short8;
typedef __attribute__((ext_vector_type(4))) float f32x4;

__device__ inline unsigned short f2bf(float f) {
  unsigned int u = __float_as_uint(f);
  u += 0x7fffu + ((u >> 16) & 1u);
  return (unsigned short)(u >> 16);
}
__device__ inline unsigned int pkbf(float a, float b) {
  __hip_bfloat162 h = __float22bfloat162_rn(make_float2(a, b));
  union { __hip_bfloat162 h2; unsigned int u; } cv;
  cv.h2 = h;
  return cv.u;
}

// transpose + cast: src [R,C] f32 -> dst [C,R] bf16
__global__ __launch_bounds__(256) void tcast_kernel(const float* __restrict__ src,
                                                    unsigned short* __restrict__ dst,
                                                    int R, int C) {
  __shared__ float tile[64][65];
  int c0 = blockIdx.x * 64, r0 = blockIdx.y * 64;
  int tx = threadIdx.x & 63, ty = threadIdx.x >> 6;
  for (int i = ty; i < 64; i += 4)
    tile[i][tx] = src[(size_t)(r0 + i) * C + c0 + tx];
  __syncthreads();
  for (int i = ty; i < 64; i += 4)
    dst[(size_t)(c0 + i) * R + r0 + tx] = f2bf(tile[tx][i]);
}

// pack key mask into 64-bit words: mpk[g] bit i = (mask[g*64+i] != 0)
__global__ __launch_bounds__(64) void maskpack_kernel(const int* __restrict__ mask,
                                                      unsigned long long* __restrict__ mpk) {
  int gid = blockIdx.x * 64 + threadIdx.x;
  unsigned long long bal = __ballot(mask[gid] != 0);
  if (threadIdx.x == 0) mpk[blockIdx.x] = bal;
}

// C = A[M,K] * Bt[N,K]^T. Block tile (MT*32) x 128, 4 waves 2x2.
// Round-7 pipeline: double-buffered LDS, ONE __syncthreads per K-step,
// prefetch issued AFTER the barrier into named regs (no lambdas, no asm:
// scratch-safe). Prefetch loads never cross a draining barrier.
// MODE 0: C0 bf16 [M,N] scaled by oscale
// MODE 1: split kv: col<512 -> C0 bf16 [M,512]; col>=512 -> C1 vt[b,h,d,m]
// MODE 2: C0 f32 [M,N] + bias
template <int MT, int MODE, bool AF32>
__global__ __launch_bounds__(256) void gemm_kernel(
    const void* __restrict__ Ap, const unsigned short* __restrict__ Bt,
    void* __restrict__ C0, unsigned short* __restrict__ C1,
    const float* __restrict__ bias, int M, int N, int K, float oscale) {
  __shared__ unsigned short As[2][MT * 32][72];
  __shared__ unsigned short Bs[2][128][72];
  const int bm = blockIdx.y * (MT * 32), bn = blockIdx.x * 128;
  const int tid = threadIdx.x;
  const int wave = tid >> 6, lane = tid & 63;
  const int wr = (wave >> 1) * (MT * 16), wc = (wave & 1) * 64;
  const int l15 = lane & 15, lq = lane >> 4;
  const int sr = tid >> 3, sc = (tid & 7) * 8;
  f32x4 acc[MT][4] = {};

  const float* Af = (const float*)Ap;
  const unsigned short* Ab = (const unsigned short*)Ap;

  float4 fa[MT][2];
  uint4 ua[MT];
  uint4 ub[4];

  // prefetch K-chunk 0
#pragma unroll
  for (int p = 0; p < MT; ++p) {
    if constexpr (AF32) {
      fa[p][0] = *(const float4*)(Af + (size_t)(bm + sr + p * 32) * K + sc);
      fa[p][1] = *(const float4*)(Af + (size_t)(bm + sr + p * 32) * K + sc + 4);
    } else {
      ua[p] = *(const uint4*)(Ab + (size_t)(bm + sr + p * 32) * K + sc);
    }
  }
#pragma unroll
  for (int p = 0; p < 4; ++p)
    ub[p] = *(const uint4*)(Bt + (size_t)(bn + sr + p * 32) * K + sc);

  for (int k0 = 0; k0 < K; k0 += 64) {
    const int buf = (k0 >> 6) & 1;
    // implicit vmcnt wait on prefetch regs here (thread-local)
#pragma unroll
    for (int p = 0; p < MT; ++p) {
      if constexpr (AF32) {
        uint4 u;
        u.x = pkbf(fa[p][0].x, fa[p][0].y);
        u.y = pkbf(fa[p][0].z, fa[p][0].w);
        u.z = pkbf(fa[p][1].x, fa[p][1].y);
        u.w = pkbf(fa[p][1].z, fa[p][1].w);
        *(uint4*)(&As[buf][sr + p * 32][sc]) = u;
      } else {
        *(uint4*)(&As[buf][sr + p * 32][sc]) = ua[p];
      }
    }
#pragma unroll
    for (int p = 0; p < 4; ++p)
      *(uint4*)(&Bs[buf][sr + p * 32][sc]) = ub[p];
    __syncthreads();  // write->read sync; prefetch below never crosses a barrier
    if (k0 + 64 < K) {
      const int kn = k0 + 64;
#pragma unroll
      for (int p = 0; p < MT; ++p) {
        if constexpr (AF32) {
          fa[p][0] = *(const float4*)(Af + (size_t)(bm + sr + p * 32) * K + kn + sc);
          fa[p][1] = *(const float4*)(Af + (size_t)(bm + sr + p * 32) * K + kn + sc + 4);
        } else {
          ua[p] = *(const uint4*)(Ab + (size_t)(bm + sr + p * 32) * K + kn + sc);
        }
      }
#pragma unroll
      for (int p = 0; p < 4; ++p)
        ub[p] = *(const uint4*)(Bt + (size_t)(bn + sr + p * 32) * K + kn + sc);
    }
#pragma unroll
    for (int kk = 0; kk < 2; ++kk) {
      short8 af[MT], bfr[4];
#pragma unroll
      for (int mt = 0; mt < MT; ++mt)
        af[mt] = *(const short8*)(&As[buf][wr + mt * 16 + l15][kk * 32 + lq * 8]);
#pragma unroll
      for (int nt = 0; nt < 4; ++nt)
        bfr[nt] = *(const short8*)(&Bs[buf][wc + nt * 16 + l15][kk * 32 + lq * 8]);
#pragma unroll
      for (int mt = 0; mt < MT; ++mt)
#pragma unroll
        for (int nt = 0; nt < 4; ++nt)
          acc[mt][nt] = __builtin_amdgcn_mfma_f32_16x16x32_bf16(af[mt], bfr[nt], acc[mt][nt], 0, 0, 0);
    }
  }

#pragma unroll
  for (int mt = 0; mt < MT; ++mt)
#pragma unroll
    for (int nt = 0; nt < 4; ++nt) {
      int row0 = bm + wr + mt * 16 + lq * 4;
      int col = bn + wc + nt * 16 + l15;
      if constexpr (MODE == 1) {
        if (col >= 512) {  // V^T path: 4 consecutive m -> one 8B store
          int bb = row0 >> 11, m = row0 & 2047;
          int hd = col - 512;  // h*64+d
          uint2 w;
          w.x = pkbf(acc[mt][nt][0], acc[mt][nt][1]);
          w.y = pkbf(acc[mt][nt][2], acc[mt][nt][3]);
          *(uint2*)(C1 + ((size_t)bb * 512 + hd) * 2048 + m) = w;
          continue;
        }
      }
#pragma unroll
      for (int j = 0; j < 4; ++j) {
        int row = row0 + j;
        float v = acc[mt][nt][j];
        if constexpr (MODE == 0) {
          ((unsigned short*)C0)[(size_t)row * N + col] = f2bf(v * oscale);
        } else if constexpr (MODE == 1) {
          ((unsigned short*)C0)[(size_t)row * 512 + col] = f2bf(v);
        } else {
          ((float*)C0)[(size_t)row * N + col] = v + bias[col];
        }
      }
    }
}

// Flash attention, swapped-MFMA in-register softmax.
// Double-buffered LDS, ONE __syncthreads per KV-tile, no inline asm, no
// lambdas (scratch-safe). 8 waves x 16 q-rows = 128 q-rows/block; 512 thr.
// Per-thread staging: 1 K uint4 + 1 V uint4 (64-row tile, 512 threads).
// Q (pre-scaled by scale*log2e) / K: [B*2048, 512] bf16. Vt: [b,h,d,m] bf16.
// blockIdx.x = bh (fast-varying -> per-XCD K/V L2 residency), blockIdx.y = q-chunk.
__global__ __launch_bounds__(512) void attn_kernel(
    const unsigned short* __restrict__ Q, const unsigned short* __restrict__ Kb,
    const unsigned short* __restrict__ Vt, const unsigned long long* __restrict__ Mpk,
    unsigned short* __restrict__ O) {
  __shared__ unsigned short Ks[2][64][72];
  __shared__ unsigned short Vs[2][64][72];
  const int b = blockIdx.x >> 3, h = blockIdx.x & 7;
  const int tid = threadIdx.x, lane = tid & 63;
  const int wave = tid >> 6;
  const int l15 = lane & 15, lq = lane >> 4;
  const int wrow = blockIdx.y * 128 + wave * 16;

  // Q fragments: lane holds q-col = l15, d-elems lq*8..+7
  short8 qf0 = *(const short8*)(Q + (size_t)(b * 2048 + wrow + l15) * 512 + h * 64 + lq * 8);
  short8 qf1 = *(const short8*)(Q + (size_t)(b * 2048 + wrow + l15) * 512 + h * 64 + 32 + lq * 8);

  f32x4 o[4] = {};  // O^T[d = dt*16+lq*4+j][q = l15]
  float mrun = -1e30f, lrun = 0.f;

  const unsigned short* Kg = Kb + (size_t)b * 2048 * 512 + h * 64;
  const unsigned short* Vg = Vt + (size_t)(b * 8 + h) * 64 * 2048;
  const unsigned long long* mp = Mpk + b * 32;

  const int str = tid >> 3;        // 0..63
  const int stc = (tid & 7) * 8;   // elem col within 64

  // prefetch tile 0 (named scalars only)
  uint4 kr = *(const uint4*)(Kg + (size_t)str * 512 + stc);
  uint4 vr = *(const uint4*)(Vg + (size_t)str * 2048 + stc);
  unsigned long long mreg = mp[0];

  for (int mb = 0; mb < 2048; mb += 64) {
    const int buf = (mb >> 6) & 1;
    // implicit vmcnt wait on kr/vr here (thread-local)
    *(uint4*)(&Ks[buf][str][stc]) = kr;
    *(uint4*)(&Vs[buf][str][stc]) = vr;
    unsigned long long mcur = mreg;
    __syncthreads();  // write->read sync for buf; prefetch below never crosses a barrier
    if (mb + 64 < 2048) {
      kr = *(const uint4*)(Kg + (size_t)(mb + 64 + str) * 512 + stc);
      vr = *(const uint4*)(Vg + (size_t)str * 2048 + mb + 64 + stc);
      mreg = mp[(mb >> 6) + 1];
    }

    // swapped QK^T: s[ct] = S^T[key = ct*16+lq*4+j][q = l15]
    f32x4 s[4] = {};
#pragma unroll
    for (int ct = 0; ct < 4; ++ct) {
      short8 kf = *(const short8*)(&Ks[buf][ct * 16 + l15][lq * 8]);
      s[ct] = __builtin_amdgcn_mfma_f32_16x16x32_bf16(kf, qf0, s[ct], 0, 0, 0);
    }
#pragma unroll
    for (int ct = 0; ct < 4; ++ct) {
      short8 kf = *(const short8*)(&Ks[buf][ct * 16 + l15][32 + lq * 8]);
      s[ct] = __builtin_amdgcn_mfma_f32_16x16x32_bf16(kf, qf1, s[ct], 0, 0, 0);
    }

    // apply mask from scalar-ized bitmask: key = ct*16 + lq*4 + j
    unsigned int mlo = __builtin_amdgcn_readfirstlane((unsigned int)mcur);
    unsigned int mhi = __builtin_amdgcn_readfirstlane((unsigned int)(mcur >> 32));
#pragma unroll
    for (int ct = 0; ct < 4; ++ct) {
      unsigned int ch = ((ct < 2) ? mlo : mhi) >> ((ct & 1) * 16);  // scalar
      unsigned int nib = (ch >> (lq * 4)) & 0xFu;
#pragma unroll
      for (int j = 0; j < 4; ++j)
        s[ct][j] = (nib & (1u << j)) ? s[ct][j] : -1e30f;
    }

    float t = -1e30f;
#pragma unroll
    for (int ct = 0; ct < 4; ++ct)
#pragma unroll
      for (int j = 0; j < 4; ++j)
        t = fmaxf(t, s[ct][j]);
    t = fmaxf(t, __shfl_xor(t, 16));
    t = fmaxf(t, __shfl_xor(t, 32));
    float mn = fmaxf(mrun, t);
    float fac = __builtin_amdgcn_exp2f(mrun - mn);
    mrun = mn;
    float rs = 0.f;
    unsigned int xp[4][2];  // bf16 pairs: keys ct*16+lq*4+{2p,2p+1}
#pragma unroll
    for (int ct = 0; ct < 4; ++ct) {
      float p0 = __builtin_amdgcn_exp2f(s[ct][0] - mn);
      float p1 = __builtin_amdgcn_exp2f(s[ct][1] - mn);
      float p2 = __builtin_amdgcn_exp2f(s[ct][2] - mn);
      float p3 = __builtin_amdgcn_exp2f(s[ct][3] - mn);
      rs += (p0 + p1) + (p2 + p3);
      xp[ct][0] = pkbf(p0, p1);
      xp[ct][1] = pkbf(p2, p3);
    }
    rs += __shfl_xor(rs, 16);
    rs += __shfl_xor(rs, 32);
    lrun = lrun * fac + rs;
#pragma unroll
    for (int dt = 0; dt < 4; ++dt)
#pragma unroll
      for (int j = 0; j < 4; ++j)
        o[dt][j] *= fac;

    // redistribute P^T into PV B-fragments:
    // dest reg r needs xp[kk*2 + (lq>>1)][r&1] from lane ((lq&1)*2 + (r>>1))*16 + l15
    unsigned int pf[2][4];
    const int slbase = ((lq & 1) * 2) * 16 + l15;
#pragma unroll
    for (int kk = 0; kk < 2; ++kk)
#pragma unroll
      for (int r = 0; r < 4; ++r) {
        int sl = (slbase + (r >> 1) * 16) << 2;
        unsigned a0 = (unsigned)__builtin_amdgcn_ds_bpermute(sl, (int)xp[kk * 2 + 0][r & 1]);
        unsigned a1 = (unsigned)__builtin_amdgcn_ds_bpermute(sl, (int)xp[kk * 2 + 1][r & 1]);
        pf[kk][r] = (lq >> 1) ? a1 : a0;
      }

    // PV swapped: O^T += V^T · P^T
#pragma unroll
    for (int kk = 0; kk < 2; ++kk) {
      union { unsigned int u[4]; short8 s8; } pc;
      pc.u[0] = pf[kk][0];
      pc.u[1] = pf[kk][1];
      pc.u[2] = pf[kk][2];
      pc.u[3] = pf[kk][3];
#pragma unroll
      for (int dt = 0; dt < 4; ++dt) {
        short8 vf = *(const short8*)(&Vs[buf][dt * 16 + l15][kk * 32 + lq * 8]);
        o[dt] = __builtin_amdgcn_mfma_f32_16x16x32_bf16(vf, pc.s8, o[dt], 0, 0, 0);
      }
    }
  }

  float rl = 1.0f / lrun;
  unsigned short* Orow = O + (size_t)(b * 2048 + wrow + l15) * 512 + h * 64;
#pragma unroll
  for (int dt = 0; dt < 4; ++dt) {
    *(unsigned int*)(Orow + dt * 16 + lq * 4)     = pkbf(o[dt][0] * rl, o[dt][1] * rl);
    *(unsigned int*)(Orow + dt * 16 + lq * 4 + 2) = pkbf(o[dt][2] * rl, o[dt][3] * rl);
  }
}

extern "C" void kernel_launch(void* const* d_in, const int* in_sizes, int n_in,
                              void* d_out, int out_size, void* d_ws, size_t ws_size,
                              hipStream_t stream) {
  const float* x       = (const float*)d_in[0];
  const float* context = (const float*)d_in[1];
  const int*   mask    = (const int*)d_in[2];
  const float* Wq      = (const float*)d_in[3];
  const float* Wkv     = (const float*)d_in[4];
  const float* Wo      = (const float*)d_in[5];
  const float* bo      = (const float*)d_in[6];
  float* out = (float*)d_out;

  char* ws = (char*)d_ws;
  unsigned short* Wq_t  = (unsigned short*)(ws + 0);         //  512x512  bf16
  unsigned short* Wkv_t = (unsigned short*)(ws + 524288);    // 1024x512  bf16
  unsigned short* Wo_t  = (unsigned short*)(ws + 1572864);   //  512x512  bf16
  unsigned short* qb    = (unsigned short*)(ws + 2097152);   // 8192x512  bf16
  unsigned short* kb    = (unsigned short*)(ws + 10485760);  // 8192x512  bf16
  unsigned short* vtb   = (unsigned short*)(ws + 18874368);  // (b,h,d)x2048 bf16
  unsigned short* ab    = (unsigned short*)(ws + 27262976);  // 8192x512  bf16
  unsigned long long* mpk = (unsigned long long*)(ws + 35651584);  // 128 x u64

  const float QSCALE = 0.125f * 1.44269504088896f;  // head_dim^-0.5 * log2(e)

  tcast_kernel<<<dim3(8, 8), 256, 0, stream>>>(Wq, Wq_t, 512, 512);
  tcast_kernel<<<dim3(16, 8), 256, 0, stream>>>(Wkv, Wkv_t, 512, 1024);
  tcast_kernel<<<dim3(8, 8), 256, 0, stream>>>(Wo, Wo_t, 512, 512);
  maskpack_kernel<<<dim3(128), 64, 0, stream>>>(mask, mpk);
  gemm_kernel<4, 0, true><<<dim3(4, 64), 256, 0, stream>>>(x, Wq_t, qb, nullptr, nullptr, 8192, 512, 512, QSCALE);
  gemm_kernel<4, 1, true><<<dim3(8, 64), 256, 0, stream>>>(context, Wkv_t, kb, vtb, nullptr, 8192, 1024, 512, 1.0f);
  attn_kernel<<<dim3(32, 16), 512, 0, stream>>>(qb, kb, vtb, mpk, ab);
  gemm_kernel<4, 2, false><<<dim3(4, 64), 256, 0, stream>>>(ab, Wo_t, out, nullptr, bo, 8192, 512, 512, 1.0f);
}